// Round 13
// baseline (6818.842 us; speedup 1.0000x reference)
//
#include <hip/hip_runtime.h>

// liGRU (2-layer) on MI355X — r12 verified base (6.79 ms) + ONE change:
// nx(t+1) prefetch moved to TOP of step (issued right after the h loads).
// r12 issued nx after sync A, putting its ~0.9us HBM latency inside the
// sync-B vmcnt(0) drain. At top-of-step, MFMA's waitcnt only needs the h
// loads (precise vmcnt(4)) and nx retires under MFMA+LDS+gate (~0.5us),
// shrinking the drain. Outputs stay in the r4-verified after-flag slot
// (r6 regression is attributed to its outputs-before-h-store half).

typedef unsigned short u16;
typedef unsigned int   u32;
typedef unsigned long long u64;
typedef __attribute__((ext_vector_type(8))) short bf16x8;
typedef __attribute__((ext_vector_type(4))) float f32x4;
typedef __attribute__((ext_vector_type(2))) float f32x2;

#define TSTEPS 512
#define BATCH  32
#define HDIM   1024
#define MROWS  (TSTEPS * BATCH)   // 16384
#define KP     2048               // split-K (hi|lo concat)
#define NWG    64

__device__ __forceinline__ u16 f2bf(float f) {
  u32 u = __float_as_uint(f);
  return (u16)((u + 0x7FFFu + ((u >> 16) & 1u)) >> 16);  // RNE
}
__device__ __forceinline__ float bf2f(u16 h) {
  return __uint_as_float(((u32)h) << 16);
}

// ---------------- cast + split: fp32 [rows][1024] -> bf16 [rows][2048] = [hi|lo]
__global__ void cast_split(const float* __restrict__ src, u16* __restrict__ dst, int total) {
  int idx = blockIdx.x * 256 + threadIdx.x;
  if (idx >= total) return;
  int m = idx >> 10, k = idx & 1023;
  float v = src[idx];
  u16 hi = f2bf(v);
  u16 lo = f2bf(v - bf2f(hi));
  dst[(size_t)m * KP + k] = hi;
  dst[(size_t)m * KP + 1024 + k] = lo;
}

// ---------------- async global->LDS, 16B per lane
__device__ __forceinline__ void stage16(const u16* g, u16* l) {
  __builtin_amdgcn_global_load_lds((const __attribute__((address_space(1))) u32*)g,
                                   (__attribute__((address_space(3))) u32*)l, 16, 0, 0);
}

// ---------------- GEMM: C[m,n] = sum_k A[m,k] * W[n,k]   (A:[M][KP], W:[1024][KP])
__global__ __launch_bounds__(256) void gemm_bt(
    const u16* __restrict__ A,
    const u16* __restrict__ Wa, const u16* __restrict__ Wb,
    float* __restrict__ Ca, float* __restrict__ Cb) {
  constexpr int BK = 64;
  const u16* W = blockIdx.z ? Wb : Wa;
  float*     C = blockIdx.z ? Cb : Ca;
  const int m0 = blockIdx.y * 128;
  const int n0 = blockIdx.x * 128;
  __shared__ __align__(16) u16 As[128 * BK];
  __shared__ __align__(16) u16 Bs[128 * BK];
  const int tid  = threadIdx.x;
  const int lane = tid & 63;
  const int wv   = tid >> 6;
  const int wm   = wv >> 1, wn = wv & 1;
  const int srow = tid >> 3;
  const int scol = (tid & 7) * 8;
  const int frow = lane & 15;
  const int kcol = (lane >> 4) * 8;

  f32x4 z4 = {0.f, 0.f, 0.f, 0.f};
  f32x4 acc[4][4];
#pragma unroll
  for (int i = 0; i < 4; ++i)
#pragma unroll
    for (int j = 0; j < 4; ++j) acc[i][j] = z4;

  for (int k0 = 0; k0 < KP; k0 += BK) {
#pragma unroll
    for (int i = 0; i < 4; ++i)
      stage16(A + (size_t)(m0 + i * 32 + srow) * KP + k0 + scol, &As[(i * 32 + srow) * BK + scol]);
#pragma unroll
    for (int i = 0; i < 4; ++i)
      stage16(W + (size_t)(n0 + i * 32 + srow) * KP + k0 + scol, &Bs[(i * 32 + srow) * BK + scol]);
    __syncthreads();
#pragma unroll
    for (int kk = 0; kk < 2; ++kk) {
      bf16x8 av[4], bv[4];
#pragma unroll
      for (int i = 0; i < 4; ++i)
        av[i] = *(const bf16x8*)&As[(wm * 64 + i * 16 + frow) * BK + kk * 32 + kcol];
#pragma unroll
      for (int j = 0; j < 4; ++j)
        bv[j] = *(const bf16x8*)&Bs[(wn * 64 + j * 16 + frow) * BK + kk * 32 + kcol];
#pragma unroll
      for (int i = 0; i < 4; ++i)
#pragma unroll
        for (int j = 0; j < 4; ++j)
          acc[i][j] = __builtin_amdgcn_mfma_f32_16x16x32_bf16(av[i], bv[j], acc[i][j], 0, 0, 0);
    }
    __syncthreads();
  }
#pragma unroll
  for (int i = 0; i < 4; ++i)
#pragma unroll
    for (int j = 0; j < 4; ++j) {
      int n  = n0 + wn * 64 + j * 16 + (lane & 15);
      int mb = m0 + wm * 64 + i * 16 + (lane >> 4) * 4;
#pragma unroll
      for (int r = 0; r < 4; ++r)
        C[(size_t)(mb + r) * HDIM + n] = acc[i][j][r];
    }
}

// ---------------- BatchNorm over batch axis, per (t,h); in-place; beta' = beta + b_rec
__global__ void bn_inplace(float* __restrict__ Pz, float* __restrict__ Ph,
                           const float* __restrict__ gz, const float* __restrict__ bz, const float* __restrict__ bhz,
                           const float* __restrict__ gh, const float* __restrict__ bh, const float* __restrict__ bhh) {
  float*       P    = blockIdx.y ? Ph  : Pz;
  const float* gam  = blockIdx.y ? gh  : gz;
  const float* bet  = blockIdx.y ? bh  : bz;
  const float* brec = blockIdx.y ? bhh : bhz;
  int idx = blockIdx.x * 256 + threadIdx.x;
  int h = idx & 1023;
  size_t base = (size_t)(idx >> 10) * (BATCH * HDIM) + h;
  float v[BATCH];
  float s = 0.f;
#pragma unroll
  for (int b = 0; b < BATCH; ++b) { v[b] = P[base + (size_t)b * HDIM]; s += v[b]; }
  float mean = s * (1.f / BATCH);
  float q = 0.f;
#pragma unroll
  for (int b = 0; b < BATCH; ++b) { float d = v[b] - mean; q += d * d; }
  float inv = rsqrtf(q * (1.f / BATCH) + 1e-5f) * gam[h];
  float add = bet[h] + brec[h];
#pragma unroll
  for (int b = 0; b < BATCH; ++b)
    P[base + (size_t)b * HDIM] = (v[b] - mean) * inv + add;
}

__global__ void init_bar(u32* flags) { flags[threadIdx.x] = 0; }  // <<<1,64>>>

// ---------------- persistent recurrence: 64 WGs x 256 threads (4 waves), 512 steps
// wave wv: half = wv>>1 (batch half), ksec = wv&1 (K half). Each wave computes
// BOTH gates (z and cand) from ONE set of h fragments; W fragments live in
// registers/AGPRs (loaded once). Cross-WG protocol (fence-free):
//   producer: atomic WT h-stores -> __syncthreads (vmcnt0: h at LLC) ->
//             relaxed flag store.  consumer: relaxed flag poll -> atomic LLC loads.
__global__ __launch_bounds__(256, 1) void ligru_rec(
    const float* __restrict__ nxz, const float* __restrict__ nxh,
    const float* __restrict__ Whz, const float* __restrict__ Whh,
    const float* __restrict__ h0,
    u16*   __restrict__ hs_bf,   // layer-1 out: [16384][2048] split bf16; or null
    float* __restrict__ hs_f,    // layer-2 out: d_out x region; or null
    float* __restrict__ hlast,   // [32][1024]
    u32*   __restrict__ hbufw,   // [2][32][512] u32 (= packed bf16 pairs)
    u32*   __restrict__ flags) {
  const int g    = blockIdx.x;
  const int c0   = g * 16;
  const int tid  = threadIdx.x;
  const int lane = tid & 63;
  const int wv   = tid >> 6;      // 0..3
  const int half = wv >> 1;       // batch half
  const int ksec = wv & 1;        // K half
  const int r    = lane & 15;     // owned column index (B-frag row) / batch row (A-frag)
  const int ko   = lane >> 4;     // k sub-offset

  __shared__ float part[2][2][2][16][17];  // [gate][ksec][half][row][col]

  // ---- W fragments -> registers (one-time). Fragment: lane holds
  // W[c0+r][ksec*512 + ko*8 + kk*32 + 0..7], split hi/lo bf16.
  bf16x8 wz_hi[16], wz_lo[16], wh_hi[16], wh_lo[16];
  {
    const float* zrow = Whz + (size_t)(c0 + r) * HDIM;
    const float* hrow = Whh + (size_t)(c0 + r) * HDIM;
#pragma unroll
    for (int kk = 0; kk < 16; ++kk) {
      int kb = ksec * 512 + ko * 8 + kk * 32;
      f32x4 z0 = *(const f32x4*)(zrow + kb);
      f32x4 z1 = *(const f32x4*)(zrow + kb + 4);
      f32x4 h0v = *(const f32x4*)(hrow + kb);
      f32x4 h1v = *(const f32x4*)(hrow + kb + 4);
      bf16x8 zh, zl, hh, hl;
#pragma unroll
      for (int j = 0; j < 4; ++j) {
        u16 a = f2bf(z0[j]);  zh[j]   = (short)a;  zl[j]   = (short)f2bf(z0[j] - bf2f(a));
        u16 b = f2bf(z1[j]);  zh[4+j] = (short)b;  zl[4+j] = (short)f2bf(z1[j] - bf2f(b));
        u16 c = f2bf(h0v[j]); hh[j]   = (short)c;  hl[j]   = (short)f2bf(h0v[j] - bf2f(c));
        u16 d = f2bf(h1v[j]); hh[4+j] = (short)d;  hl[4+j] = (short)f2bf(h1v[j] - bf2f(d));
      }
      wz_hi[kk] = zh; wz_lo[kk] = zl; wh_hi[kk] = hh; wh_lo[kk] = hl;
    }
  }

  // ---- per-thread h state: (bb = tid>>3, column pair cA=2*cp, cB=2*cp+1)
  const int bb = tid >> 3;    // batch 0..31
  const int cp = tid & 7;     // col pair 0..7
  const int bh_ = bb >> 4, br_ = bb & 15;
  float hr0 = h0[(size_t)bb * HDIM + c0 + 2 * cp];
  float hr1 = h0[(size_t)bb * HDIM + c0 + 2 * cp + 1];
  {
    u32 p = (u32)f2bf(hr0) | ((u32)f2bf(hr1) << 16);
    __hip_atomic_store(hbufw + (size_t)bb * 512 + g * 8 + cp, p,
                       __ATOMIC_RELAXED, __HIP_MEMORY_SCOPE_AGENT);
  }
  __syncthreads();  // drain h0 broadcast stores (vmcnt 0)
  if (tid == 0)
    __hip_atomic_store(&flags[g], 1u, __ATOMIC_RELAXED, __HIP_MEMORY_SCOPE_AGENT);
  {
    for (;;) {
      u32 f = __hip_atomic_load(&flags[lane], __ATOMIC_RELAXED, __HIP_MEMORY_SCOPE_AGENT);
      if (__all(f >= 1u)) break;
    }
  }

  const size_t hb64base = (size_t)(half * 16 + r) * 256 + ksec * 128 + ko * 2;  // u64 units
  f32x4 z4 = {0.f, 0.f, 0.f, 0.f};

  // nx for t=0 (current)
  f32x2 nxz_c = *(const f32x2*)(nxz + (size_t)bb * HDIM + c0 + 2 * cp);
  f32x2 nxh_c = *(const f32x2*)(nxh + (size_t)bb * HDIM + c0 + 2 * cp);

  for (int t = 0; t < TSTEPS; ++t) {
    const u64* hb64 = (const u64*)(hbufw + (size_t)(t & 1) * (BATCH * 512));
    u32*       hbn  = hbufw + (size_t)((t + 1) & 1) * (BATCH * 512);

    // h fragments: 32 u64 agent-scope LLC loads (issued first — in-order retire)
    u64 hw[32];
#pragma unroll
    for (int kk = 0; kk < 16; ++kk) {
      hw[2 * kk]     = __hip_atomic_load(hb64 + hb64base + kk * 8,
                                         __ATOMIC_RELAXED, __HIP_MEMORY_SCOPE_AGENT);
      hw[2 * kk + 1] = __hip_atomic_load(hb64 + hb64base + kk * 8 + 1,
                                         __ATOMIC_RELAXED, __HIP_MEMORY_SCOPE_AGENT);
    }

    // nx(t+1) prefetch at TOP (after h loads): MFMA's precise waitcnt covers
    // only the h loads; nx retires under MFMA+LDS+gate, NOT in the sync-B drain.
    int tn = (t + 1 < TSTEPS) ? t + 1 : t;
    f32x2 nxz_n = *(const f32x2*)(nxz + (size_t)(tn * BATCH + bb) * HDIM + c0 + 2 * cp);
    f32x2 nxh_n = *(const f32x2*)(nxh + (size_t)(tn * BATCH + bb) * HDIM + c0 + 2 * cp);

    // MFMA: both gates, hi+lo W, 4 independent 16-deep chains
    f32x4 az0 = z4, az1 = z4, ac0 = z4, ac1 = z4;
#pragma unroll
    for (int kk = 0; kk < 16; ++kk) {
      union { u64 d[2]; bf16x8 v; } a;
      a.d[0] = hw[2 * kk];
      a.d[1] = hw[2 * kk + 1];
      az0 = __builtin_amdgcn_mfma_f32_16x16x32_bf16(a.v, wz_hi[kk], az0, 0, 0, 0);
      az1 = __builtin_amdgcn_mfma_f32_16x16x32_bf16(a.v, wz_lo[kk], az1, 0, 0, 0);
      ac0 = __builtin_amdgcn_mfma_f32_16x16x32_bf16(a.v, wh_hi[kk], ac0, 0, 0, 0);
      ac1 = __builtin_amdgcn_mfma_f32_16x16x32_bf16(a.v, wh_lo[kk], ac1, 0, 0, 0);
    }
    f32x4 sz = az0 + az1;
    f32x4 sc = ac0 + ac1;

    // D layout: col = lane&15 (= r), row = 4*ko + reg
#pragma unroll
    for (int reg = 0; reg < 4; ++reg) {
      part[0][ksec][half][ko * 4 + reg][r] = sz[reg];
      part[1][ksec][half][ko * 4 + reg][r] = sc[reg];
    }
    __syncthreads();  // sync A: partials visible

    // gate math for the two owned columns
    float zp0 = part[0][0][bh_][br_][2 * cp]     + part[0][1][bh_][br_][2 * cp]     + nxz_c[0];
    float zp1 = part[0][0][bh_][br_][2 * cp + 1] + part[0][1][bh_][br_][2 * cp + 1] + nxz_c[1];
    float cp0 = part[1][0][bh_][br_][2 * cp]     + part[1][1][bh_][br_][2 * cp]     + nxh_c[0];
    float cp1 = part[1][0][bh_][br_][2 * cp + 1] + part[1][1][bh_][br_][2 * cp + 1] + nxh_c[1];
    float zg0 = 1.f / (1.f + __expf(-zp0));
    float zg1 = 1.f / (1.f + __expf(-zp1));
    float cd0 = fmaxf(cp0, 0.f);
    float cd1 = fmaxf(cp1, 0.f);
    float hn0 = zg0 * hr0 + (1.f - zg0) * cd0;
    float hn1 = zg1 * hr1 + (1.f - zg1) * cd1;
    hr0 = hn0; hr1 = hn1;

    u16 hi0 = f2bf(hn0), hi1 = f2bf(hn1);
    u32 p = (u32)hi0 | ((u32)hi1 << 16);
    __hip_atomic_store(hbn + (size_t)bb * 512 + g * 8 + cp, p,
                       __ATOMIC_RELAXED, __HIP_MEMORY_SCOPE_AGENT);
    __syncthreads();  // sync B: all waves' h stores drained (vmcnt 0) -> at LLC
    if (tid == 0)
      __hip_atomic_store(&flags[g], (u32)(t + 2), __ATOMIC_RELAXED, __HIP_MEMORY_SCOPE_AGENT);

    // output stores AFTER flag (drain during poll)
    if (hs_f) {
      f32x2 o = {hn0, hn1};
      *(f32x2*)(hs_f + (size_t)(t * BATCH + bb) * HDIM + c0 + 2 * cp) = o;
    } else {
      size_t row = (size_t)(t * BATCH + bb) * KP;
      *(u32*)(hs_bf + row + c0 + 2 * cp) = p;
      u32 plo = (u32)f2bf(hn0 - bf2f(hi0)) | ((u32)f2bf(hn1 - bf2f(hi1)) << 16);
      *(u32*)(hs_bf + row + 1024 + c0 + 2 * cp) = plo;
    }

    if (t == TSTEPS - 1) {
      f32x2 o = {hn0, hn1};
      *(f32x2*)(hlast + (size_t)bb * HDIM + c0 + 2 * cp) = o;
    } else {
      u32 tgt = (u32)(t + 2);
      for (;;) {
        u32 f = __hip_atomic_load(&flags[lane], __ATOMIC_RELAXED, __HIP_MEMORY_SCOPE_AGENT);
        if (__all(f >= tgt)) break;
      }
    }
    nxz_c = nxz_n; nxh_c = nxh_n;
  }
}

// ---------------- host
extern "C" void kernel_launch(void* const* d_in, const int* in_sizes, int n_in,
                              void* d_out, int out_size, void* d_ws, size_t ws_size,
                              hipStream_t stream) {
  const float* x   = (const float*)d_in[0];
  const float* h0  = (const float*)d_in[1];
  const float* Wxz = (const float*)d_in[2];
  // d_in[3] = bxz: cancels inside BatchNorm -> unused
  const float* gz  = (const float*)d_in[4];
  const float* bz  = (const float*)d_in[5];
  const float* Whz = (const float*)d_in[6];
  const float* bhz = (const float*)d_in[7];
  const float* Wxh = (const float*)d_in[8];
  // d_in[9] = bxh: cancels in BN -> unused
  const float* gh  = (const float*)d_in[10];
  const float* bh  = (const float*)d_in[11];
  const float* Whh = (const float*)d_in[12];
  const float* bhh = (const float*)d_in[13];

  float* out_x = (float*)d_out;
  float* out_h = out_x + (size_t)MROWS * HDIM;

  char* w = (char*)d_ws;
  u16* xsp = (u16*)w;  w += (size_t)MROWS * KP * 2;            // 64 MB
  u16* wxp[4];
  for (int i = 0; i < 4; ++i) { wxp[i] = (u16*)w; w += (size_t)HDIM * KP * 2; }  // 4x4MB
  float* Pz = (float*)w;  w += (size_t)MROWS * HDIM * 4;       // 64 MB
  float* Ph = (float*)w;  w += (size_t)MROWS * HDIM * 4;       // 64 MB
  u32* hbufw = (u32*)w;   w += (size_t)2 * BATCH * 512 * 4;    // 128 KB
  u32* flags = (u32*)w;   w += 64 * 4;

  cast_split<<<(MROWS * HDIM + 255) / 256, 256, 0, stream>>>(x, xsp, MROWS * HDIM);
  for (int l = 0; l < 2; ++l) {
    cast_split<<<(HDIM * HDIM + 255) / 256, 256, 0, stream>>>(Wxz + (size_t)l * HDIM * HDIM, wxp[l * 2 + 0], HDIM * HDIM);
    cast_split<<<(HDIM * HDIM + 255) / 256, 256, 0, stream>>>(Wxh + (size_t)l * HDIM * HDIM, wxp[l * 2 + 1], HDIM * HDIM);
  }

  for (int l = 0; l < 2; ++l) {
    dim3 gg(HDIM / 128, MROWS / 128, 2);
    gemm_bt<<<gg, 256, 0, stream>>>(xsp, wxp[l * 2 + 0], wxp[l * 2 + 1], Pz, Ph);
    bn_inplace<<<dim3((TSTEPS * HDIM) / 256, 2), 256, 0, stream>>>(
        Pz, Ph,
        gz + (size_t)l * HDIM, bz + (size_t)l * HDIM, bhz + (size_t)l * HDIM,
        gh + (size_t)l * HDIM, bh + (size_t)l * HDIM, bhh + (size_t)l * HDIM);
    init_bar<<<1, 64, 0, stream>>>(flags);
    ligru_rec<<<NWG, 256, 0, stream>>>(
        Pz, Ph,
        Whz + (size_t)l * HDIM * HDIM, Whh + (size_t)l * HDIM * HDIM, h0,
        (l == 0) ? xsp : (u16*)nullptr,
        (l == 0) ? (float*)nullptr : out_x,
        out_h + (size_t)l * BATCH * HDIM,
        hbufw, flags);
  }
}

// Round 14
// 5423.089 us; speedup vs baseline: 1.2574x; 1.2574x over previous
//
#include <hip/hip_runtime.h>

// liGRU (2-layer) on MI355X — r13 verified base (3263 us/rec) + ONE change:
// the per-step h-exchange loads are fused: each lane's 16 contiguous bytes
// (2x u64 at hb64base+kk*8) become ONE inline-asm global_load_dwordx4 with
// sc0 sc1 (same device-coherence path the agent-scope atomic lowers to).
// 16 instructions/lane instead of 32, 16B/transaction instead of 8B ->
// halves the LLC transaction count of the exchange burst. Fencing per
// guide rule #18: s_waitcnt vmcnt(0) + sched_barrier(0) before consumers;
// compiler memory fence after the poll pins the loads below it.

typedef unsigned short u16;
typedef unsigned int   u32;
typedef unsigned long long u64;
typedef __attribute__((ext_vector_type(8))) short bf16x8;
typedef __attribute__((ext_vector_type(4))) float f32x4;
typedef __attribute__((ext_vector_type(2))) float f32x2;
typedef __attribute__((ext_vector_type(4))) unsigned int u32x4;

#define TSTEPS 512
#define BATCH  32
#define HDIM   1024
#define MROWS  (TSTEPS * BATCH)   // 16384
#define KP     2048               // split-K (hi|lo concat)
#define NWG    64

__device__ __forceinline__ u16 f2bf(float f) {
  u32 u = __float_as_uint(f);
  return (u16)((u + 0x7FFFu + ((u >> 16) & 1u)) >> 16);  // RNE
}
__device__ __forceinline__ float bf2f(u16 h) {
  return __uint_as_float(((u32)h) << 16);
}

// ---------------- cast + split: fp32 [rows][1024] -> bf16 [rows][2048] = [hi|lo]
__global__ void cast_split(const float* __restrict__ src, u16* __restrict__ dst, int total) {
  int idx = blockIdx.x * 256 + threadIdx.x;
  if (idx >= total) return;
  int m = idx >> 10, k = idx & 1023;
  float v = src[idx];
  u16 hi = f2bf(v);
  u16 lo = f2bf(v - bf2f(hi));
  dst[(size_t)m * KP + k] = hi;
  dst[(size_t)m * KP + 1024 + k] = lo;
}

// ---------------- async global->LDS, 16B per lane
__device__ __forceinline__ void stage16(const u16* g, u16* l) {
  __builtin_amdgcn_global_load_lds((const __attribute__((address_space(1))) u32*)g,
                                   (__attribute__((address_space(3))) u32*)l, 16, 0, 0);
}

// ---------------- GEMM: C[m,n] = sum_k A[m,k] * W[n,k]   (A:[M][KP], W:[1024][KP])
__global__ __launch_bounds__(256) void gemm_bt(
    const u16* __restrict__ A,
    const u16* __restrict__ Wa, const u16* __restrict__ Wb,
    float* __restrict__ Ca, float* __restrict__ Cb) {
  constexpr int BK = 64;
  const u16* W = blockIdx.z ? Wb : Wa;
  float*     C = blockIdx.z ? Cb : Ca;
  const int m0 = blockIdx.y * 128;
  const int n0 = blockIdx.x * 128;
  __shared__ __align__(16) u16 As[128 * BK];
  __shared__ __align__(16) u16 Bs[128 * BK];
  const int tid  = threadIdx.x;
  const int lane = tid & 63;
  const int wv   = tid >> 6;
  const int wm   = wv >> 1, wn = wv & 1;
  const int srow = tid >> 3;
  const int scol = (tid & 7) * 8;
  const int frow = lane & 15;
  const int kcol = (lane >> 4) * 8;

  f32x4 z4 = {0.f, 0.f, 0.f, 0.f};
  f32x4 acc[4][4];
#pragma unroll
  for (int i = 0; i < 4; ++i)
#pragma unroll
    for (int j = 0; j < 4; ++j) acc[i][j] = z4;

  for (int k0 = 0; k0 < KP; k0 += BK) {
#pragma unroll
    for (int i = 0; i < 4; ++i)
      stage16(A + (size_t)(m0 + i * 32 + srow) * KP + k0 + scol, &As[(i * 32 + srow) * BK + scol]);
#pragma unroll
    for (int i = 0; i < 4; ++i)
      stage16(W + (size_t)(n0 + i * 32 + srow) * KP + k0 + scol, &Bs[(i * 32 + srow) * BK + scol]);
    __syncthreads();
#pragma unroll
    for (int kk = 0; kk < 2; ++kk) {
      bf16x8 av[4], bv[4];
#pragma unroll
      for (int i = 0; i < 4; ++i)
        av[i] = *(const bf16x8*)&As[(wm * 64 + i * 16 + frow) * BK + kk * 32 + kcol];
#pragma unroll
      for (int j = 0; j < 4; ++j)
        bv[j] = *(const bf16x8*)&Bs[(wn * 64 + j * 16 + frow) * BK + kk * 32 + kcol];
#pragma unroll
      for (int i = 0; i < 4; ++i)
#pragma unroll
        for (int j = 0; j < 4; ++j)
          acc[i][j] = __builtin_amdgcn_mfma_f32_16x16x32_bf16(av[i], bv[j], acc[i][j], 0, 0, 0);
    }
    __syncthreads();
  }
#pragma unroll
  for (int i = 0; i < 4; ++i)
#pragma unroll
    for (int j = 0; j < 4; ++j) {
      int n  = n0 + wn * 64 + j * 16 + (lane & 15);
      int mb = m0 + wm * 64 + i * 16 + (lane >> 4) * 4;
#pragma unroll
      for (int r = 0; r < 4; ++r)
        C[(size_t)(mb + r) * HDIM + n] = acc[i][j][r];
    }
}

// ---------------- BatchNorm over batch axis, per (t,h); in-place; beta' = beta + b_rec
__global__ void bn_inplace(float* __restrict__ Pz, float* __restrict__ Ph,
                           const float* __restrict__ gz, const float* __restrict__ bz, const float* __restrict__ bhz,
                           const float* __restrict__ gh, const float* __restrict__ bh, const float* __restrict__ bhh) {
  float*       P    = blockIdx.y ? Ph  : Pz;
  const float* gam  = blockIdx.y ? gh  : gz;
  const float* bet  = blockIdx.y ? bh  : bz;
  const float* brec = blockIdx.y ? bhh : bhz;
  int idx = blockIdx.x * 256 + threadIdx.x;
  int h = idx & 1023;
  size_t base = (size_t)(idx >> 10) * (BATCH * HDIM) + h;
  float v[BATCH];
  float s = 0.f;
#pragma unroll
  for (int b = 0; b < BATCH; ++b) { v[b] = P[base + (size_t)b * HDIM]; s += v[b]; }
  float mean = s * (1.f / BATCH);
  float q = 0.f;
#pragma unroll
  for (int b = 0; b < BATCH; ++b) { float d = v[b] - mean; q += d * d; }
  float inv = rsqrtf(q * (1.f / BATCH) + 1e-5f) * gam[h];
  float add = bet[h] + brec[h];
#pragma unroll
  for (int b = 0; b < BATCH; ++b)
    P[base + (size_t)b * HDIM] = (v[b] - mean) * inv + add;
}

__global__ void init_bar(u32* flags) { flags[threadIdx.x] = 0; }  // <<<1,64>>>

// ---------------- persistent recurrence: 64 WGs x 256 threads (4 waves), 512 steps
// wave wv: half = wv>>1 (batch half), ksec = wv&1 (K half). Each wave computes
// BOTH gates (z and cand) from ONE set of h fragments; W fragments live in
// registers/AGPRs (loaded once). Cross-WG protocol (fence-free):
//   producer: atomic WT h-stores -> __syncthreads (vmcnt0: h at LLC) ->
//             relaxed flag store.  consumer: relaxed flag poll -> dwordx4
//             sc0/sc1 loads (device-coherent, LLC-served).
__global__ __launch_bounds__(256, 1) void ligru_rec(
    const float* __restrict__ nxz, const float* __restrict__ nxh,
    const float* __restrict__ Whz, const float* __restrict__ Whh,
    const float* __restrict__ h0,
    u16*   __restrict__ hs_bf,   // layer-1 out: [16384][2048] split bf16; or null
    float* __restrict__ hs_f,    // layer-2 out: d_out x region; or null
    float* __restrict__ hlast,   // [32][1024]
    u32*   __restrict__ hbufw,   // [2][32][512] u32 (= packed bf16 pairs)
    u32*   __restrict__ flags) {
  const int g    = blockIdx.x;
  const int c0   = g * 16;
  const int tid  = threadIdx.x;
  const int lane = tid & 63;
  const int wv   = tid >> 6;      // 0..3
  const int half = wv >> 1;       // batch half
  const int ksec = wv & 1;        // K half
  const int r    = lane & 15;     // owned column index (B-frag row) / batch row (A-frag)
  const int ko   = lane >> 4;     // k sub-offset

  __shared__ float part[2][2][2][16][17];  // [gate][ksec][half][row][col]

  // ---- W fragments -> registers (one-time). Fragment: lane holds
  // W[c0+r][ksec*512 + ko*8 + kk*32 + 0..7], split hi/lo bf16.
  bf16x8 wz_hi[16], wz_lo[16], wh_hi[16], wh_lo[16];
  {
    const float* zrow = Whz + (size_t)(c0 + r) * HDIM;
    const float* hrow = Whh + (size_t)(c0 + r) * HDIM;
#pragma unroll
    for (int kk = 0; kk < 16; ++kk) {
      int kb = ksec * 512 + ko * 8 + kk * 32;
      f32x4 z0 = *(const f32x4*)(zrow + kb);
      f32x4 z1 = *(const f32x4*)(zrow + kb + 4);
      f32x4 h0v = *(const f32x4*)(hrow + kb);
      f32x4 h1v = *(const f32x4*)(hrow + kb + 4);
      bf16x8 zh, zl, hh, hl;
#pragma unroll
      for (int j = 0; j < 4; ++j) {
        u16 a = f2bf(z0[j]);  zh[j]   = (short)a;  zl[j]   = (short)f2bf(z0[j] - bf2f(a));
        u16 b = f2bf(z1[j]);  zh[4+j] = (short)b;  zl[4+j] = (short)f2bf(z1[j] - bf2f(b));
        u16 c = f2bf(h0v[j]); hh[j]   = (short)c;  hl[j]   = (short)f2bf(h0v[j] - bf2f(c));
        u16 d = f2bf(h1v[j]); hh[4+j] = (short)d;  hl[4+j] = (short)f2bf(h1v[j] - bf2f(d));
      }
      wz_hi[kk] = zh; wz_lo[kk] = zl; wh_hi[kk] = hh; wh_lo[kk] = hl;
    }
  }

  // ---- per-thread h state: (bb = tid>>3, column pair cA=2*cp, cB=2*cp+1)
  const int bb = tid >> 3;    // batch 0..31
  const int cp = tid & 7;     // col pair 0..7
  const int bh_ = bb >> 4, br_ = bb & 15;
  float hr0 = h0[(size_t)bb * HDIM + c0 + 2 * cp];
  float hr1 = h0[(size_t)bb * HDIM + c0 + 2 * cp + 1];
  {
    u32 p = (u32)f2bf(hr0) | ((u32)f2bf(hr1) << 16);
    __hip_atomic_store(hbufw + (size_t)bb * 512 + g * 8 + cp, p,
                       __ATOMIC_RELAXED, __HIP_MEMORY_SCOPE_AGENT);
  }
  __syncthreads();  // drain h0 broadcast stores (vmcnt 0)
  if (tid == 0)
    __hip_atomic_store(&flags[g], 1u, __ATOMIC_RELAXED, __HIP_MEMORY_SCOPE_AGENT);
  {
    for (;;) {
      u32 f = __hip_atomic_load(&flags[lane], __ATOMIC_RELAXED, __HIP_MEMORY_SCOPE_AGENT);
      if (__all(f >= 1u)) break;
    }
  }

  const size_t hb64base = (size_t)(half * 16 + r) * 256 + ksec * 128 + ko * 2;  // u64 units
  f32x4 z4 = {0.f, 0.f, 0.f, 0.f};

  // nx for t=0 (current)
  f32x2 nxz_c = *(const f32x2*)(nxz + (size_t)bb * HDIM + c0 + 2 * cp);
  f32x2 nxh_c = *(const f32x2*)(nxh + (size_t)bb * HDIM + c0 + 2 * cp);

  for (int t = 0; t < TSTEPS; ++t) {
    const u64* hb64 = (const u64*)(hbufw + (size_t)(t & 1) * (BATCH * 512));
    u32*       hbn  = hbufw + (size_t)((t + 1) & 1) * (BATCH * 512);

    // h fragments: 16 x global_load_dwordx4 sc0 sc1 (device-coherent, 16B each).
    // The asm is pinned below the poll by the memory fence; consumers are
    // pinned below the waitcnt by sched_barrier(0) (guide rule #18).
    asm volatile("" ::: "memory");
    const u64* hbp = hb64 + hb64base;
    u32x4 hw4[16];
#pragma unroll
    for (int kk = 0; kk < 16; ++kk)
      asm volatile("global_load_dwordx4 %0, %1, off offset:%2 sc0 sc1"
                   : "=v"(hw4[kk])
                   : "v"(hbp), "i"(kk * 64));
    asm volatile("s_waitcnt vmcnt(0)" ::: "memory");
    __builtin_amdgcn_sched_barrier(0);

    // nx(t+1) prefetch AFTER the wait: retires under MFMA+LDS+gate phases.
    int tn = (t + 1 < TSTEPS) ? t + 1 : t;
    f32x2 nxz_n = *(const f32x2*)(nxz + (size_t)(tn * BATCH + bb) * HDIM + c0 + 2 * cp);
    f32x2 nxh_n = *(const f32x2*)(nxh + (size_t)(tn * BATCH + bb) * HDIM + c0 + 2 * cp);

    // MFMA: both gates, hi+lo W, 4 independent 16-deep chains
    f32x4 az0 = z4, az1 = z4, ac0 = z4, ac1 = z4;
#pragma unroll
    for (int kk = 0; kk < 16; ++kk) {
      union { u32x4 q; bf16x8 v; } a;
      a.q = hw4[kk];
      az0 = __builtin_amdgcn_mfma_f32_16x16x32_bf16(a.v, wz_hi[kk], az0, 0, 0, 0);
      az1 = __builtin_amdgcn_mfma_f32_16x16x32_bf16(a.v, wz_lo[kk], az1, 0, 0, 0);
      ac0 = __builtin_amdgcn_mfma_f32_16x16x32_bf16(a.v, wh_hi[kk], ac0, 0, 0, 0);
      ac1 = __builtin_amdgcn_mfma_f32_16x16x32_bf16(a.v, wh_lo[kk], ac1, 0, 0, 0);
    }
    f32x4 sz = az0 + az1;
    f32x4 sc = ac0 + ac1;

    // D layout: col = lane&15 (= r), row = 4*ko + reg
#pragma unroll
    for (int reg = 0; reg < 4; ++reg) {
      part[0][ksec][half][ko * 4 + reg][r] = sz[reg];
      part[1][ksec][half][ko * 4 + reg][r] = sc[reg];
    }
    __syncthreads();  // sync A: partials visible

    // gate math for the two owned columns
    float zp0 = part[0][0][bh_][br_][2 * cp]     + part[0][1][bh_][br_][2 * cp]     + nxz_c[0];
    float zp1 = part[0][0][bh_][br_][2 * cp + 1] + part[0][1][bh_][br_][2 * cp + 1] + nxz_c[1];
    float cp0 = part[1][0][bh_][br_][2 * cp]     + part[1][1][bh_][br_][2 * cp]     + nxh_c[0];
    float cp1 = part[1][0][bh_][br_][2 * cp + 1] + part[1][1][bh_][br_][2 * cp + 1] + nxh_c[1];
    float zg0 = 1.f / (1.f + __expf(-zp0));
    float zg1 = 1.f / (1.f + __expf(-zp1));
    float cd0 = fmaxf(cp0, 0.f);
    float cd1 = fmaxf(cp1, 0.f);
    float hn0 = zg0 * hr0 + (1.f - zg0) * cd0;
    float hn1 = zg1 * hr1 + (1.f - zg1) * cd1;
    hr0 = hn0; hr1 = hn1;

    u16 hi0 = f2bf(hn0), hi1 = f2bf(hn1);
    u32 p = (u32)hi0 | ((u32)hi1 << 16);
    __hip_atomic_store(hbn + (size_t)bb * 512 + g * 8 + cp, p,
                       __ATOMIC_RELAXED, __HIP_MEMORY_SCOPE_AGENT);
    __syncthreads();  // sync B: all waves' h stores drained (vmcnt 0) -> at LLC
    if (tid == 0)
      __hip_atomic_store(&flags[g], (u32)(t + 2), __ATOMIC_RELAXED, __HIP_MEMORY_SCOPE_AGENT);

    // output stores AFTER flag (drain during poll)
    if (hs_f) {
      f32x2 o = {hn0, hn1};
      *(f32x2*)(hs_f + (size_t)(t * BATCH + bb) * HDIM + c0 + 2 * cp) = o;
    } else {
      size_t row = (size_t)(t * BATCH + bb) * KP;
      *(u32*)(hs_bf + row + c0 + 2 * cp) = p;
      u32 plo = (u32)f2bf(hn0 - bf2f(hi0)) | ((u32)f2bf(hn1 - bf2f(hi1)) << 16);
      *(u32*)(hs_bf + row + 1024 + c0 + 2 * cp) = plo;
    }

    if (t == TSTEPS - 1) {
      f32x2 o = {hn0, hn1};
      *(f32x2*)(hlast + (size_t)bb * HDIM + c0 + 2 * cp) = o;
    } else {
      u32 tgt = (u32)(t + 2);
      for (;;) {
        u32 f = __hip_atomic_load(&flags[lane], __ATOMIC_RELAXED, __HIP_MEMORY_SCOPE_AGENT);
        if (__all(f >= tgt)) break;
      }
    }
    nxz_c = nxz_n; nxh_c = nxh_n;
  }
}

// ---------------- host
extern "C" void kernel_launch(void* const* d_in, const int* in_sizes, int n_in,
                              void* d_out, int out_size, void* d_ws, size_t ws_size,
                              hipStream_t stream) {
  const float* x   = (const float*)d_in[0];
  const float* h0  = (const float*)d_in[1];
  const float* Wxz = (const float*)d_in[2];
  // d_in[3] = bxz: cancels inside BatchNorm -> unused
  const float* gz  = (const float*)d_in[4];
  const float* bz  = (const float*)d_in[5];
  const float* Whz = (const float*)d_in[6];
  const float* bhz = (const float*)d_in[7];
  const float* Wxh = (const float*)d_in[8];
  // d_in[9] = bxh: cancels in BN -> unused
  const float* gh  = (const float*)d_in[10];
  const float* bh  = (const float*)d_in[11];
  const float* Whh = (const float*)d_in[12];
  const float* bhh = (const float*)d_in[13];

  float* out_x = (float*)d_out;
  float* out_h = out_x + (size_t)MROWS * HDIM;

  char* w = (char*)d_ws;
  u16* xsp = (u16*)w;  w += (size_t)MROWS * KP * 2;            // 64 MB
  u16* wxp[4];
  for (int i = 0; i < 4; ++i) { wxp[i] = (u16*)w; w += (size_t)HDIM * KP * 2; }  // 4x4MB
  float* Pz = (float*)w;  w += (size_t)MROWS * HDIM * 4;       // 64 MB
  float* Ph = (float*)w;  w += (size_t)MROWS * HDIM * 4;       // 64 MB
  u32* hbufw = (u32*)w;   w += (size_t)2 * BATCH * 512 * 4;    // 128 KB
  u32* flags = (u32*)w;   w += 64 * 4;

  cast_split<<<(MROWS * HDIM + 255) / 256, 256, 0, stream>>>(x, xsp, MROWS * HDIM);
  for (int l = 0; l < 2; ++l) {
    cast_split<<<(HDIM * HDIM + 255) / 256, 256, 0, stream>>>(Wxz + (size_t)l * HDIM * HDIM, wxp[l * 2 + 0], HDIM * HDIM);
    cast_split<<<(HDIM * HDIM + 255) / 256, 256, 0, stream>>>(Wxh + (size_t)l * HDIM * HDIM, wxp[l * 2 + 1], HDIM * HDIM);
  }

  for (int l = 0; l < 2; ++l) {
    dim3 gg(HDIM / 128, MROWS / 128, 2);
    gemm_bt<<<gg, 256, 0, stream>>>(xsp, wxp[l * 2 + 0], wxp[l * 2 + 1], Pz, Ph);
    bn_inplace<<<dim3((TSTEPS * HDIM) / 256, 2), 256, 0, stream>>>(
        Pz, Ph,
        gz + (size_t)l * HDIM, bz + (size_t)l * HDIM, bhz + (size_t)l * HDIM,
        gh + (size_t)l * HDIM, bh + (size_t)l * HDIM, bhh + (size_t)l * HDIM);
    init_bar<<<1, 64, 0, stream>>>(flags);
    ligru_rec<<<NWG, 256, 0, stream>>>(
        Pz, Ph,
        Whz + (size_t)l * HDIM * HDIM, Whh + (size_t)l * HDIM * HDIM, h0,
        (l == 0) ? xsp : (u16*)nullptr,
        (l == 0) ? (float*)nullptr : out_x,
        out_h + (size_t)l * BATCH * HDIM,
        hbufw, flags);
  }
}

// Round 15
// 5272.255 us; speedup vs baseline: 1.2933x; 1.0286x over previous
//
#include <hip/hip_runtime.h>

// liGRU (2-layer) on MI355X — r14 verified base (2477 us/rec) + ONE mechanism:
// STORE-side transaction packing (mirror of r14's load-side win).
//   h-broadcast: 4 lanes (same batch row, cp-aligned) pack u32x4 via shfl_down,
//     one lane issues global_store_dwordx4 sc0 sc1  (256 -> 64 stores/WG/step)
//   hs_bf hi/lo planes: same packing, plain cached stores (512 -> 128)
//   out_x: lane-pair packing of f32x2 (256 -> 128)
// Sync-B __syncthreads still emits vmcnt(0) (nx loads are compiler-tracked),
// draining the asm h-store before the flag — protocol unchanged.

typedef unsigned short u16;
typedef unsigned int   u32;
typedef unsigned long long u64;
typedef __attribute__((ext_vector_type(8))) short bf16x8;
typedef __attribute__((ext_vector_type(4))) float f32x4;
typedef __attribute__((ext_vector_type(2))) float f32x2;
typedef __attribute__((ext_vector_type(4))) unsigned int u32x4;
typedef __attribute__((ext_vector_type(4))) float f32x4v;

#define TSTEPS 512
#define BATCH  32
#define HDIM   1024
#define MROWS  (TSTEPS * BATCH)   // 16384
#define KP     2048               // split-K (hi|lo concat)
#define NWG    64

__device__ __forceinline__ u16 f2bf(float f) {
  u32 u = __float_as_uint(f);
  return (u16)((u + 0x7FFFu + ((u >> 16) & 1u)) >> 16);  // RNE
}
__device__ __forceinline__ float bf2f(u16 h) {
  return __uint_as_float(((u32)h) << 16);
}

// ---------------- cast + split: fp32 [rows][1024] -> bf16 [rows][2048] = [hi|lo]
__global__ void cast_split(const float* __restrict__ src, u16* __restrict__ dst, int total) {
  int idx = blockIdx.x * 256 + threadIdx.x;
  if (idx >= total) return;
  int m = idx >> 10, k = idx & 1023;
  float v = src[idx];
  u16 hi = f2bf(v);
  u16 lo = f2bf(v - bf2f(hi));
  dst[(size_t)m * KP + k] = hi;
  dst[(size_t)m * KP + 1024 + k] = lo;
}

// ---------------- async global->LDS, 16B per lane
__device__ __forceinline__ void stage16(const u16* g, u16* l) {
  __builtin_amdgcn_global_load_lds((const __attribute__((address_space(1))) u32*)g,
                                   (__attribute__((address_space(3))) u32*)l, 16, 0, 0);
}

// ---------------- GEMM: C[m,n] = sum_k A[m,k] * W[n,k]   (A:[M][KP], W:[1024][KP])
__global__ __launch_bounds__(256) void gemm_bt(
    const u16* __restrict__ A,
    const u16* __restrict__ Wa, const u16* __restrict__ Wb,
    float* __restrict__ Ca, float* __restrict__ Cb) {
  constexpr int BK = 64;
  const u16* W = blockIdx.z ? Wb : Wa;
  float*     C = blockIdx.z ? Cb : Ca;
  const int m0 = blockIdx.y * 128;
  const int n0 = blockIdx.x * 128;
  __shared__ __align__(16) u16 As[128 * BK];
  __shared__ __align__(16) u16 Bs[128 * BK];
  const int tid  = threadIdx.x;
  const int lane = tid & 63;
  const int wv   = tid >> 6;
  const int wm   = wv >> 1, wn = wv & 1;
  const int srow = tid >> 3;
  const int scol = (tid & 7) * 8;
  const int frow = lane & 15;
  const int kcol = (lane >> 4) * 8;

  f32x4 z4 = {0.f, 0.f, 0.f, 0.f};
  f32x4 acc[4][4];
#pragma unroll
  for (int i = 0; i < 4; ++i)
#pragma unroll
    for (int j = 0; j < 4; ++j) acc[i][j] = z4;

  for (int k0 = 0; k0 < KP; k0 += BK) {
#pragma unroll
    for (int i = 0; i < 4; ++i)
      stage16(A + (size_t)(m0 + i * 32 + srow) * KP + k0 + scol, &As[(i * 32 + srow) * BK + scol]);
#pragma unroll
    for (int i = 0; i < 4; ++i)
      stage16(W + (size_t)(n0 + i * 32 + srow) * KP + k0 + scol, &Bs[(i * 32 + srow) * BK + scol]);
    __syncthreads();
#pragma unroll
    for (int kk = 0; kk < 2; ++kk) {
      bf16x8 av[4], bv[4];
#pragma unroll
      for (int i = 0; i < 4; ++i)
        av[i] = *(const bf16x8*)&As[(wm * 64 + i * 16 + frow) * BK + kk * 32 + kcol];
#pragma unroll
      for (int j = 0; j < 4; ++j)
        bv[j] = *(const bf16x8*)&Bs[(wn * 64 + j * 16 + frow) * BK + kk * 32 + kcol];
#pragma unroll
      for (int i = 0; i < 4; ++i)
#pragma unroll
        for (int j = 0; j < 4; ++j)
          acc[i][j] = __builtin_amdgcn_mfma_f32_16x16x32_bf16(av[i], bv[j], acc[i][j], 0, 0, 0);
    }
    __syncthreads();
  }
#pragma unroll
  for (int i = 0; i < 4; ++i)
#pragma unroll
    for (int j = 0; j < 4; ++j) {
      int n  = n0 + wn * 64 + j * 16 + (lane & 15);
      int mb = m0 + wm * 64 + i * 16 + (lane >> 4) * 4;
#pragma unroll
      for (int r = 0; r < 4; ++r)
        C[(size_t)(mb + r) * HDIM + n] = acc[i][j][r];
    }
}

// ---------------- BatchNorm over batch axis, per (t,h); in-place; beta' = beta + b_rec
__global__ void bn_inplace(float* __restrict__ Pz, float* __restrict__ Ph,
                           const float* __restrict__ gz, const float* __restrict__ bz, const float* __restrict__ bhz,
                           const float* __restrict__ gh, const float* __restrict__ bh, const float* __restrict__ bhh) {
  float*       P    = blockIdx.y ? Ph  : Pz;
  const float* gam  = blockIdx.y ? gh  : gz;
  const float* bet  = blockIdx.y ? bh  : bz;
  const float* brec = blockIdx.y ? bhh : bhz;
  int idx = blockIdx.x * 256 + threadIdx.x;
  int h = idx & 1023;
  size_t base = (size_t)(idx >> 10) * (BATCH * HDIM) + h;
  float v[BATCH];
  float s = 0.f;
#pragma unroll
  for (int b = 0; b < BATCH; ++b) { v[b] = P[base + (size_t)b * HDIM]; s += v[b]; }
  float mean = s * (1.f / BATCH);
  float q = 0.f;
#pragma unroll
  for (int b = 0; b < BATCH; ++b) { float d = v[b] - mean; q += d * d; }
  float inv = rsqrtf(q * (1.f / BATCH) + 1e-5f) * gam[h];
  float add = bet[h] + brec[h];
#pragma unroll
  for (int b = 0; b < BATCH; ++b)
    P[base + (size_t)b * HDIM] = (v[b] - mean) * inv + add;
}

__global__ void init_bar(u32* flags) { flags[threadIdx.x] = 0; }  // <<<1,64>>>

// ---------------- persistent recurrence: 64 WGs x 256 threads (4 waves), 512 steps
__global__ __launch_bounds__(256, 1) void ligru_rec(
    const float* __restrict__ nxz, const float* __restrict__ nxh,
    const float* __restrict__ Whz, const float* __restrict__ Whh,
    const float* __restrict__ h0,
    u16*   __restrict__ hs_bf,   // layer-1 out: [16384][2048] split bf16; or null
    float* __restrict__ hs_f,    // layer-2 out: d_out x region; or null
    float* __restrict__ hlast,   // [32][1024]
    u32*   __restrict__ hbufw,   // [2][32][512] u32 (= packed bf16 pairs)
    u32*   __restrict__ flags) {
  const int g    = blockIdx.x;
  const int c0   = g * 16;
  const int tid  = threadIdx.x;
  const int lane = tid & 63;
  const int wv   = tid >> 6;      // 0..3
  const int half = wv >> 1;       // batch half
  const int ksec = wv & 1;        // K half
  const int r    = lane & 15;
  const int ko   = lane >> 4;

  __shared__ float part[2][2][2][16][17];  // [gate][ksec][half][row][col]

  // ---- W fragments -> registers (one-time), hi/lo split (r4-identical)
  bf16x8 wz_hi[16], wz_lo[16], wh_hi[16], wh_lo[16];
  {
    const float* zrow = Whz + (size_t)(c0 + r) * HDIM;
    const float* hrow = Whh + (size_t)(c0 + r) * HDIM;
#pragma unroll
    for (int kk = 0; kk < 16; ++kk) {
      int kb = ksec * 512 + ko * 8 + kk * 32;
      f32x4 z0 = *(const f32x4*)(zrow + kb);
      f32x4 z1 = *(const f32x4*)(zrow + kb + 4);
      f32x4 h0v = *(const f32x4*)(hrow + kb);
      f32x4 h1v = *(const f32x4*)(hrow + kb + 4);
      bf16x8 zh, zl, hh, hl;
#pragma unroll
      for (int j = 0; j < 4; ++j) {
        u16 a = f2bf(z0[j]);  zh[j]   = (short)a;  zl[j]   = (short)f2bf(z0[j] - bf2f(a));
        u16 b = f2bf(z1[j]);  zh[4+j] = (short)b;  zl[4+j] = (short)f2bf(z1[j] - bf2f(b));
        u16 c = f2bf(h0v[j]); hh[j]   = (short)c;  hl[j]   = (short)f2bf(h0v[j] - bf2f(c));
        u16 d = f2bf(h1v[j]); hh[4+j] = (short)d;  hl[4+j] = (short)f2bf(h1v[j] - bf2f(d));
      }
      wz_hi[kk] = zh; wz_lo[kk] = zl; wh_hi[kk] = hh; wh_lo[kk] = hl;
    }
  }

  // ---- per-thread h state: (bb = tid>>3, column pair 2*cp, 2*cp+1)
  const int bb = tid >> 3;
  const int cp = tid & 7;
  const int bh_ = bb >> 4, br_ = bb & 15;
  float hr0 = h0[(size_t)bb * HDIM + c0 + 2 * cp];
  float hr1 = h0[(size_t)bb * HDIM + c0 + 2 * cp + 1];
  {
    u32 p = (u32)f2bf(hr0) | ((u32)f2bf(hr1) << 16);
    __hip_atomic_store(hbufw + (size_t)bb * 512 + g * 8 + cp, p,
                       __ATOMIC_RELAXED, __HIP_MEMORY_SCOPE_AGENT);
  }
  __syncthreads();  // drain h0 broadcast stores (vmcnt 0)
  if (tid == 0)
    __hip_atomic_store(&flags[g], 1u, __ATOMIC_RELAXED, __HIP_MEMORY_SCOPE_AGENT);
  {
    for (;;) {
      u32 f = __hip_atomic_load(&flags[lane], __ATOMIC_RELAXED, __HIP_MEMORY_SCOPE_AGENT);
      if (__all(f >= 1u)) break;
    }
  }

  const size_t hb64base = (size_t)(half * 16 + r) * 256 + ksec * 128 + ko * 2;  // u64 units
  f32x4 z4 = {0.f, 0.f, 0.f, 0.f};

  // nx for t=0 (current)
  f32x2 nxz_c = *(const f32x2*)(nxz + (size_t)bb * HDIM + c0 + 2 * cp);
  f32x2 nxh_c = *(const f32x2*)(nxh + (size_t)bb * HDIM + c0 + 2 * cp);

  for (int t = 0; t < TSTEPS; ++t) {
    const u64* hb64 = (const u64*)(hbufw + (size_t)(t & 1) * (BATCH * 512));
    u32*       hbn  = hbufw + (size_t)((t + 1) & 1) * (BATCH * 512);

    // h fragments: 16 x global_load_dwordx4 sc0 sc1 (device-coherent, 16B each)
    asm volatile("" ::: "memory");
    const u64* hbp = hb64 + hb64base;
    u32x4 hw4[16];
#pragma unroll
    for (int kk = 0; kk < 16; ++kk)
      asm volatile("global_load_dwordx4 %0, %1, off offset:%2 sc0 sc1"
                   : "=v"(hw4[kk])
                   : "v"(hbp), "i"(kk * 64));
    asm volatile("s_waitcnt vmcnt(0)" ::: "memory");
    __builtin_amdgcn_sched_barrier(0);

    // nx(t+1) prefetch AFTER the wait: retires under MFMA+LDS+gate phases.
    int tn = (t + 1 < TSTEPS) ? t + 1 : t;
    f32x2 nxz_n = *(const f32x2*)(nxz + (size_t)(tn * BATCH + bb) * HDIM + c0 + 2 * cp);
    f32x2 nxh_n = *(const f32x2*)(nxh + (size_t)(tn * BATCH + bb) * HDIM + c0 + 2 * cp);

    // MFMA: both gates, hi+lo W, 4 independent 16-deep chains
    f32x4 az0 = z4, az1 = z4, ac0 = z4, ac1 = z4;
#pragma unroll
    for (int kk = 0; kk < 16; ++kk) {
      union { u32x4 q; bf16x8 v; } a;
      a.q = hw4[kk];
      az0 = __builtin_amdgcn_mfma_f32_16x16x32_bf16(a.v, wz_hi[kk], az0, 0, 0, 0);
      az1 = __builtin_amdgcn_mfma_f32_16x16x32_bf16(a.v, wz_lo[kk], az1, 0, 0, 0);
      ac0 = __builtin_amdgcn_mfma_f32_16x16x32_bf16(a.v, wh_hi[kk], ac0, 0, 0, 0);
      ac1 = __builtin_amdgcn_mfma_f32_16x16x32_bf16(a.v, wh_lo[kk], ac1, 0, 0, 0);
    }
    f32x4 sz = az0 + az1;
    f32x4 sc = ac0 + ac1;

    // D layout: col = lane&15 (= r), row = 4*ko + reg
#pragma unroll
    for (int reg = 0; reg < 4; ++reg) {
      part[0][ksec][half][ko * 4 + reg][r] = sz[reg];
      part[1][ksec][half][ko * 4 + reg][r] = sc[reg];
    }
    __syncthreads();  // sync A: partials visible

    // gate math for the two owned columns
    float zp0 = part[0][0][bh_][br_][2 * cp]     + part[0][1][bh_][br_][2 * cp]     + nxz_c[0];
    float zp1 = part[0][0][bh_][br_][2 * cp + 1] + part[0][1][bh_][br_][2 * cp + 1] + nxz_c[1];
    float cp0 = part[1][0][bh_][br_][2 * cp]     + part[1][1][bh_][br_][2 * cp]     + nxh_c[0];
    float cp1 = part[1][0][bh_][br_][2 * cp + 1] + part[1][1][bh_][br_][2 * cp + 1] + nxh_c[1];
    float zg0 = 1.f / (1.f + __expf(-zp0));
    float zg1 = 1.f / (1.f + __expf(-zp1));
    float cd0 = fmaxf(cp0, 0.f);
    float cd1 = fmaxf(cp1, 0.f);
    float hn0 = zg0 * hr0 + (1.f - zg0) * cd0;
    float hn1 = zg1 * hr1 + (1.f - zg1) * cd1;
    hr0 = hn0; hr1 = hn1;

    u16 hi0 = f2bf(hn0), hi1 = f2bf(hn1);
    u32 p   = (u32)hi0 | ((u32)hi1 << 16);
    u32 plo = (u32)f2bf(hn0 - bf2f(hi0)) | ((u32)f2bf(hn1 - bf2f(hi1)) << 16);

    // ---- packed h-broadcast: 4 lanes (same bb, cp group) -> one dwordx4 sc0 sc1
    u32 p1 = __shfl_down(p, 1);
    u32 p2 = __shfl_down(p, 2);
    u32 p3 = __shfl_down(p, 3);
    if ((tid & 3) == 0) {
      u32x4 pk4 = {p, p1, p2, p3};
      u32* dst = hbn + (size_t)bb * 512 + g * 8 + cp;   // cp in {0,4}: 16B aligned
      asm volatile("global_store_dwordx4 %0, %1, off sc0 sc1"
                   :: "v"(dst), "v"(pk4) : "memory");
    }
    __syncthreads();  // sync B: vmcnt(0) (nx tracked) drains the h store -> at LLC
    if (tid == 0)
      __hip_atomic_store(&flags[g], (u32)(t + 2), __ATOMIC_RELAXED, __HIP_MEMORY_SCOPE_AGENT);

    // ---- output stores AFTER flag (packed, plain cached: dispatch-boundary flush)
    if (hs_f) {
      float o1a = __shfl_down(hn0, 1);
      float o1b = __shfl_down(hn1, 1);
      if ((tid & 1) == 0) {
        f32x4v o4 = {hn0, hn1, o1a, o1b};
        float* dst = hs_f + (size_t)(t * BATCH + bb) * HDIM + c0 + 2 * cp;  // cp even: 16B aligned
        asm volatile("global_store_dwordx4 %0, %1, off" :: "v"(dst), "v"(o4) : "memory");
      }
    } else {
      u32 q1 = __shfl_down(plo, 1);
      u32 q2 = __shfl_down(plo, 2);
      u32 q3 = __shfl_down(plo, 3);
      if ((tid & 3) == 0) {
        u32* hs32 = (u32*)hs_bf;
        size_t base = ((size_t)(t * BATCH + bb) * KP + c0) / 2 + cp;  // u32 units, 16B aligned
        u32x4 h4 = {p, p1, p2, p3};
        u32x4 l4 = {plo, q1, q2, q3};
        asm volatile("global_store_dwordx4 %0, %1, off" :: "v"(hs32 + base), "v"(h4) : "memory");
        asm volatile("global_store_dwordx4 %0, %1, off" :: "v"(hs32 + base + 512), "v"(l4) : "memory");
      }
    }

    if (t == TSTEPS - 1) {
      f32x2 o = {hn0, hn1};
      *(f32x2*)(hlast + (size_t)bb * HDIM + c0 + 2 * cp) = o;
    } else {
      u32 tgt = (u32)(t + 2);
      for (;;) {
        u32 f = __hip_atomic_load(&flags[lane], __ATOMIC_RELAXED, __HIP_MEMORY_SCOPE_AGENT);
        if (__all(f >= tgt)) break;
      }
    }
    nxz_c = nxz_n; nxh_c = nxh_n;
  }
}

// ---------------- host
extern "C" void kernel_launch(void* const* d_in, const int* in_sizes, int n_in,
                              void* d_out, int out_size, void* d_ws, size_t ws_size,
                              hipStream_t stream) {
  const float* x   = (const float*)d_in[0];
  const float* h0  = (const float*)d_in[1];
  const float* Wxz = (const float*)d_in[2];
  // d_in[3] = bxz: cancels inside BatchNorm -> unused
  const float* gz  = (const float*)d_in[4];
  const float* bz  = (const float*)d_in[5];
  const float* Whz = (const float*)d_in[6];
  const float* bhz = (const float*)d_in[7];
  const float* Wxh = (const float*)d_in[8];
  // d_in[9] = bxh: cancels in BN -> unused
  const float* gh  = (const float*)d_in[10];
  const float* bh  = (const float*)d_in[11];
  const float* Whh = (const float*)d_in[12];
  const float* bhh = (const float*)d_in[13];

  float* out_x = (float*)d_out;
  float* out_h = out_x + (size_t)MROWS * HDIM;

  char* w = (char*)d_ws;
  u16* xsp = (u16*)w;  w += (size_t)MROWS * KP * 2;            // 64 MB
  u16* wxp[4];
  for (int i = 0; i < 4; ++i) { wxp[i] = (u16*)w; w += (size_t)HDIM * KP * 2; }  // 4x4MB
  float* Pz = (float*)w;  w += (size_t)MROWS * HDIM * 4;       // 64 MB
  float* Ph = (float*)w;  w += (size_t)MROWS * HDIM * 4;       // 64 MB
  u32* hbufw = (u32*)w;   w += (size_t)2 * BATCH * 512 * 4;    // 128 KB
  u32* flags = (u32*)w;   w += 64 * 4;

  cast_split<<<(MROWS * HDIM + 255) / 256, 256, 0, stream>>>(x, xsp, MROWS * HDIM);
  for (int l = 0; l < 2; ++l) {
    cast_split<<<(HDIM * HDIM + 255) / 256, 256, 0, stream>>>(Wxz + (size_t)l * HDIM * HDIM, wxp[l * 2 + 0], HDIM * HDIM);
    cast_split<<<(HDIM * HDIM + 255) / 256, 256, 0, stream>>>(Wxh + (size_t)l * HDIM * HDIM, wxp[l * 2 + 1], HDIM * HDIM);
  }

  for (int l = 0; l < 2; ++l) {
    dim3 gg(HDIM / 128, MROWS / 128, 2);
    gemm_bt<<<gg, 256, 0, stream>>>(xsp, wxp[l * 2 + 0], wxp[l * 2 + 1], Pz, Ph);
    bn_inplace<<<dim3((TSTEPS * HDIM) / 256, 2), 256, 0, stream>>>(
        Pz, Ph,
        gz + (size_t)l * HDIM, bz + (size_t)l * HDIM, bhz + (size_t)l * HDIM,
        gh + (size_t)l * HDIM, bh + (size_t)l * HDIM, bhh + (size_t)l * HDIM);
    init_bar<<<1, 64, 0, stream>>>(flags);
    ligru_rec<<<NWG, 256, 0, stream>>>(
        Pz, Ph,
        Whz + (size_t)l * HDIM * HDIM, Whh + (size_t)l * HDIM * HDIM, h0,
        (l == 0) ? xsp : (u16*)nullptr,
        (l == 0) ? (float*)nullptr : out_x,
        out_h + (size_t)l * BATCH * HDIM,
        hbufw, flags);
  }
}

// Round 16
// 4772.811 us; speedup vs baseline: 1.4287x; 1.1046x over previous
//
#include <hip/hip_runtime.h>

// liGRU (2-layer) on MI355X — r15 base (2389 us/rec) + ONE structural change:
// 32 WGs x 32 columns (was 64 x 16). Each WG still reads the full 64KB h per
// step, so chip-wide LLC read traffic HALVES (4MB -> 2MB/step, 262K -> 131K
// transactions) — r14/r15 established ~0.19ns/transaction as the limiter.
// Register budget for 32 columns is paid by dropping the recurrence W_lo
// plane (single-bf16 W): W rounding error (~0.2% rel) is half the accepted
// single-bf16 h error, absmax expected ~0.05 (threshold 0.117).
// W regs: 2 gates x 2 colgroups x 16kk x 4 VGPR = 256 (same as before).

typedef unsigned short u16;
typedef unsigned int   u32;
typedef unsigned long long u64;
typedef __attribute__((ext_vector_type(8))) short bf16x8;
typedef __attribute__((ext_vector_type(4))) float f32x4;
typedef __attribute__((ext_vector_type(2))) float f32x2;
typedef __attribute__((ext_vector_type(4))) unsigned int u32x4;

#define TSTEPS 512
#define BATCH  32
#define HDIM   1024
#define MROWS  (TSTEPS * BATCH)   // 16384
#define KP     2048               // split-K (hi|lo concat) for input GEMM
#define NWG    32                 // recurrence WGs (32 cols each)

__device__ __forceinline__ u16 f2bf(float f) {
  u32 u = __float_as_uint(f);
  return (u16)((u + 0x7FFFu + ((u >> 16) & 1u)) >> 16);  // RNE
}
__device__ __forceinline__ float bf2f(u16 h) {
  return __uint_as_float(((u32)h) << 16);
}

// ---------------- cast + split: fp32 [rows][1024] -> bf16 [rows][2048] = [hi|lo]
__global__ void cast_split(const float* __restrict__ src, u16* __restrict__ dst, int total) {
  int idx = blockIdx.x * 256 + threadIdx.x;
  if (idx >= total) return;
  int m = idx >> 10, k = idx & 1023;
  float v = src[idx];
  u16 hi = f2bf(v);
  u16 lo = f2bf(v - bf2f(hi));
  dst[(size_t)m * KP + k] = hi;
  dst[(size_t)m * KP + 1024 + k] = lo;
}

// ---------------- async global->LDS, 16B per lane
__device__ __forceinline__ void stage16(const u16* g, u16* l) {
  __builtin_amdgcn_global_load_lds((const __attribute__((address_space(1))) u32*)g,
                                   (__attribute__((address_space(3))) u32*)l, 16, 0, 0);
}

// ---------------- GEMM: C[m,n] = sum_k A[m,k] * W[n,k]   (A:[M][KP], W:[1024][KP])
__global__ __launch_bounds__(256) void gemm_bt(
    const u16* __restrict__ A,
    const u16* __restrict__ Wa, const u16* __restrict__ Wb,
    float* __restrict__ Ca, float* __restrict__ Cb) {
  constexpr int BK = 64;
  const u16* W = blockIdx.z ? Wb : Wa;
  float*     C = blockIdx.z ? Cb : Ca;
  const int m0 = blockIdx.y * 128;
  const int n0 = blockIdx.x * 128;
  __shared__ __align__(16) u16 As[128 * BK];
  __shared__ __align__(16) u16 Bs[128 * BK];
  const int tid  = threadIdx.x;
  const int lane = tid & 63;
  const int wv   = tid >> 6;
  const int wm   = wv >> 1, wn = wv & 1;
  const int srow = tid >> 3;
  const int scol = (tid & 7) * 8;
  const int frow = lane & 15;
  const int kcol = (lane >> 4) * 8;

  f32x4 z4 = {0.f, 0.f, 0.f, 0.f};
  f32x4 acc[4][4];
#pragma unroll
  for (int i = 0; i < 4; ++i)
#pragma unroll
    for (int j = 0; j < 4; ++j) acc[i][j] = z4;

  for (int k0 = 0; k0 < KP; k0 += BK) {
#pragma unroll
    for (int i = 0; i < 4; ++i)
      stage16(A + (size_t)(m0 + i * 32 + srow) * KP + k0 + scol, &As[(i * 32 + srow) * BK + scol]);
#pragma unroll
    for (int i = 0; i < 4; ++i)
      stage16(W + (size_t)(n0 + i * 32 + srow) * KP + k0 + scol, &Bs[(i * 32 + srow) * BK + scol]);
    __syncthreads();
#pragma unroll
    for (int kk = 0; kk < 2; ++kk) {
      bf16x8 av[4], bv[4];
#pragma unroll
      for (int i = 0; i < 4; ++i)
        av[i] = *(const bf16x8*)&As[(wm * 64 + i * 16 + frow) * BK + kk * 32 + kcol];
#pragma unroll
      for (int j = 0; j < 4; ++j)
        bv[j] = *(const bf16x8*)&Bs[(wn * 64 + j * 16 + frow) * BK + kk * 32 + kcol];
#pragma unroll
      for (int i = 0; i < 4; ++i)
#pragma unroll
        for (int j = 0; j < 4; ++j)
          acc[i][j] = __builtin_amdgcn_mfma_f32_16x16x32_bf16(av[i], bv[j], acc[i][j], 0, 0, 0);
    }
    __syncthreads();
  }
#pragma unroll
  for (int i = 0; i < 4; ++i)
#pragma unroll
    for (int j = 0; j < 4; ++j) {
      int n  = n0 + wn * 64 + j * 16 + (lane & 15);
      int mb = m0 + wm * 64 + i * 16 + (lane >> 4) * 4;
#pragma unroll
      for (int r = 0; r < 4; ++r)
        C[(size_t)(mb + r) * HDIM + n] = acc[i][j][r];
    }
}

// ---------------- BatchNorm over batch axis, per (t,h); in-place; beta' = beta + b_rec
__global__ void bn_inplace(float* __restrict__ Pz, float* __restrict__ Ph,
                           const float* __restrict__ gz, const float* __restrict__ bz, const float* __restrict__ bhz,
                           const float* __restrict__ gh, const float* __restrict__ bh, const float* __restrict__ bhh) {
  float*       P    = blockIdx.y ? Ph  : Pz;
  const float* gam  = blockIdx.y ? gh  : gz;
  const float* bet  = blockIdx.y ? bh  : bz;
  const float* brec = blockIdx.y ? bhh : bhz;
  int idx = blockIdx.x * 256 + threadIdx.x;
  int h = idx & 1023;
  size_t base = (size_t)(idx >> 10) * (BATCH * HDIM) + h;
  float v[BATCH];
  float s = 0.f;
#pragma unroll
  for (int b = 0; b < BATCH; ++b) { v[b] = P[base + (size_t)b * HDIM]; s += v[b]; }
  float mean = s * (1.f / BATCH);
  float q = 0.f;
#pragma unroll
  for (int b = 0; b < BATCH; ++b) { float d = v[b] - mean; q += d * d; }
  float inv = rsqrtf(q * (1.f / BATCH) + 1e-5f) * gam[h];
  float add = bet[h] + brec[h];
#pragma unroll
  for (int b = 0; b < BATCH; ++b)
    P[base + (size_t)b * HDIM] = (v[b] - mean) * inv + add;
}

__global__ void init_bar(u32* flags) { flags[threadIdx.x] = 0; }  // <<<1,64>>>

// ---------------- persistent recurrence: 32 WGs x 256 threads (4 waves), 512 steps
// WG owns 32 columns (c0 = g*32). wave wv: half = wv>>1 (batch half),
// ksec = wv&1 (K half). Per kk: ONE h A-fragment feeds 4 MFMA
// (2 gates x 2 column-groups). W single-plane bf16 in registers.
// Cross-WG protocol identical to r4/r14/r15 (verified).
__global__ __launch_bounds__(256, 1) void ligru_rec(
    const float* __restrict__ nxz, const float* __restrict__ nxh,
    const float* __restrict__ Whz, const float* __restrict__ Whh,
    const float* __restrict__ h0,
    u16*   __restrict__ hs_bf,   // layer-1 out: [16384][2048] split bf16; or null
    float* __restrict__ hs_f,    // layer-2 out: d_out x region; or null
    float* __restrict__ hlast,   // [32][1024]
    u32*   __restrict__ hbufw,   // [2][32][512] u32 (= packed bf16 pairs)
    u32*   __restrict__ flags) { // [32] per-WG flags
  const int g    = blockIdx.x;     // 0..31
  const int c0   = g * 32;         // owned columns c0..c0+31
  const int tid  = threadIdx.x;
  const int lane = tid & 63;
  const int wv   = tid >> 6;       // 0..3
  const int half = wv >> 1;        // batch half
  const int ksec = wv & 1;         // K half
  const int r    = lane & 15;
  const int ko   = lane >> 4;

  __shared__ float part[2][2][2][16][33];  // [gate][ksec][half][row][col 0..31]

  // ---- W fragments -> registers (single bf16 plane). Lane holds, per
  // colgroup cg: W[c0+cg*16+r][ksec*512 + ko*8 + kk*32 + 0..7].
  bf16x8 wz[2][16], wh[2][16];
#pragma unroll
  for (int cg = 0; cg < 2; ++cg) {
    const float* zrow = Whz + (size_t)(c0 + cg * 16 + r) * HDIM;
    const float* hrow = Whh + (size_t)(c0 + cg * 16 + r) * HDIM;
#pragma unroll
    for (int kk = 0; kk < 16; ++kk) {
      int kb = ksec * 512 + ko * 8 + kk * 32;
      f32x4 z0 = *(const f32x4*)(zrow + kb);
      f32x4 z1 = *(const f32x4*)(zrow + kb + 4);
      f32x4 h0v = *(const f32x4*)(hrow + kb);
      f32x4 h1v = *(const f32x4*)(hrow + kb + 4);
      bf16x8 zv, hv;
#pragma unroll
      for (int j = 0; j < 4; ++j) {
        zv[j]     = (short)f2bf(z0[j]);
        zv[4 + j] = (short)f2bf(z1[j]);
        hv[j]     = (short)f2bf(h0v[j]);
        hv[4 + j] = (short)f2bf(h1v[j]);
      }
      wz[cg][kk] = zv; wh[cg][kk] = hv;
    }
  }

  // ---- per-thread h state: batch bb = tid>>3, columns c0 + 4*cp .. +3
  const int bb = tid >> 3;
  const int cp = tid & 7;
  const int bh_ = bb >> 4, br_ = bb & 15;
  f32x4 hr = *(const f32x4*)(h0 + (size_t)bb * HDIM + c0 + 4 * cp);
  {
    u32 p0 = (u32)f2bf(hr[0]) | ((u32)f2bf(hr[1]) << 16);
    u32 p1 = (u32)f2bf(hr[2]) | ((u32)f2bf(hr[3]) << 16);
    u32* dst = hbufw + (size_t)bb * 512 + g * 16 + 2 * cp;
    __hip_atomic_store(dst,     p0, __ATOMIC_RELAXED, __HIP_MEMORY_SCOPE_AGENT);
    __hip_atomic_store(dst + 1, p1, __ATOMIC_RELAXED, __HIP_MEMORY_SCOPE_AGENT);
  }
  __syncthreads();  // drain h0 broadcast stores (vmcnt 0)
  if (tid == 0)
    __hip_atomic_store(&flags[g], 1u, __ATOMIC_RELAXED, __HIP_MEMORY_SCOPE_AGENT);
  {
    for (;;) {
      u32 f = __hip_atomic_load(&flags[lane & 31], __ATOMIC_RELAXED, __HIP_MEMORY_SCOPE_AGENT);
      if (__all(f >= 1u)) break;
    }
  }

  const size_t hb64base = (size_t)(half * 16 + r) * 256 + ksec * 128 + ko * 2;  // u64 units
  f32x4 z4 = {0.f, 0.f, 0.f, 0.f};

  // nx for t=0 (current): 4 owned columns
  f32x4 nxz_c = *(const f32x4*)(nxz + (size_t)bb * HDIM + c0 + 4 * cp);
  f32x4 nxh_c = *(const f32x4*)(nxh + (size_t)bb * HDIM + c0 + 4 * cp);

  for (int t = 0; t < TSTEPS; ++t) {
    const u64* hb64 = (const u64*)(hbufw + (size_t)(t & 1) * (BATCH * 512));
    u32*       hbn  = hbufw + (size_t)((t + 1) & 1) * (BATCH * 512);

    // h fragments: 16 x global_load_dwordx4 sc0 sc1 (device-coherent)
    asm volatile("" ::: "memory");
    const u64* hbp = hb64 + hb64base;
    u32x4 hw4[16];
#pragma unroll
    for (int kk = 0; kk < 16; ++kk)
      asm volatile("global_load_dwordx4 %0, %1, off offset:%2 sc0 sc1"
                   : "=v"(hw4[kk])
                   : "v"(hbp), "i"(kk * 64));
    asm volatile("s_waitcnt vmcnt(0)" ::: "memory");
    __builtin_amdgcn_sched_barrier(0);

    // nx(t+1) prefetch AFTER the wait: retires under MFMA+LDS+gate phases.
    int tn = (t + 1 < TSTEPS) ? t + 1 : t;
    f32x4 nxz_n = *(const f32x4*)(nxz + (size_t)(tn * BATCH + bb) * HDIM + c0 + 4 * cp);
    f32x4 nxh_n = *(const f32x4*)(nxh + (size_t)(tn * BATCH + bb) * HDIM + c0 + 4 * cp);

    // MFMA: one A-frag feeds 4 chains (2 gates x 2 colgroups), 16 deep
    f32x4 az0 = z4, az1 = z4, ac0 = z4, ac1 = z4;
#pragma unroll
    for (int kk = 0; kk < 16; ++kk) {
      union { u32x4 q; bf16x8 v; } a;
      a.q = hw4[kk];
      az0 = __builtin_amdgcn_mfma_f32_16x16x32_bf16(a.v, wz[0][kk], az0, 0, 0, 0);
      az1 = __builtin_amdgcn_mfma_f32_16x16x32_bf16(a.v, wz[1][kk], az1, 0, 0, 0);
      ac0 = __builtin_amdgcn_mfma_f32_16x16x32_bf16(a.v, wh[0][kk], ac0, 0, 0, 0);
      ac1 = __builtin_amdgcn_mfma_f32_16x16x32_bf16(a.v, wh[1][kk], ac1, 0, 0, 0);
    }

    // D layout: col = cg*16 + r, row = 4*ko + reg
#pragma unroll
    for (int reg = 0; reg < 4; ++reg) {
      part[0][ksec][half][ko * 4 + reg][r]      = az0[reg];
      part[0][ksec][half][ko * 4 + reg][16 + r] = az1[reg];
      part[1][ksec][half][ko * 4 + reg][r]      = ac0[reg];
      part[1][ksec][half][ko * 4 + reg][16 + r] = ac1[reg];
    }
    __syncthreads();  // sync A: partials visible

    // gate math for the four owned columns
    f32x4 hn;
#pragma unroll
    for (int j = 0; j < 4; ++j) {
      int col = 4 * cp + j;
      float zp = part[0][0][bh_][br_][col] + part[0][1][bh_][br_][col] + nxz_c[j];
      float cq = part[1][0][bh_][br_][col] + part[1][1][bh_][br_][col] + nxh_c[j];
      float zg = 1.f / (1.f + __expf(-zp));
      float cd = fmaxf(cq, 0.f);
      hn[j] = zg * hr[j] + (1.f - zg) * cd;
    }
    hr = hn;

    u16 h0b = f2bf(hn[0]), h1b = f2bf(hn[1]), h2b = f2bf(hn[2]), h3b = f2bf(hn[3]);
    u32 p0 = (u32)h0b | ((u32)h1b << 16);
    u32 p1 = (u32)h2b | ((u32)h3b << 16);

    // ---- packed h-broadcast: lane pair (cp even/odd) -> one dwordx4 sc0 sc1
    u32 p0n = __shfl_down(p0, 1);
    u32 p1n = __shfl_down(p1, 1);
    if ((tid & 1) == 0) {
      u32x4 pk4 = {p0, p1, p0n, p1n};
      u32* dst = hbn + (size_t)bb * 512 + g * 16 + 2 * cp;  // cp even: 16B aligned
      asm volatile("global_store_dwordx4 %0, %1, off sc0 sc1"
                   :: "v"(dst), "v"(pk4) : "memory");
    }
    __syncthreads();  // sync B: vmcnt(0) (nx tracked) drains the h store -> at LLC
    if (tid == 0)
      __hip_atomic_store(&flags[g], (u32)(t + 2), __ATOMIC_RELAXED, __HIP_MEMORY_SCOPE_AGENT);

    // ---- output stores AFTER flag (plain cached; dispatch-boundary flush)
    if (hs_f) {
      *(f32x4*)(hs_f + (size_t)(t * BATCH + bb) * HDIM + c0 + 4 * cp) = hn;
    } else {
      u32 l0 = (u32)f2bf(hn[0] - bf2f(h0b)) | ((u32)f2bf(hn[1] - bf2f(h1b)) << 16);
      u32 l1 = (u32)f2bf(hn[2] - bf2f(h2b)) | ((u32)f2bf(hn[3] - bf2f(h3b)) << 16);
      u32 l0n = __shfl_down(l0, 1);
      u32 l1n = __shfl_down(l1, 1);
      if ((tid & 1) == 0) {
        u32* hs32 = (u32*)hs_bf;
        size_t base = (size_t)(t * BATCH + bb) * (KP / 2) + g * 16 + 2 * cp;  // u32 units
        u32x4 h4 = {p0, p1, p0n, p1n};
        u32x4 l4 = {l0, l1, l0n, l1n};
        asm volatile("global_store_dwordx4 %0, %1, off" :: "v"(hs32 + base), "v"(h4) : "memory");
        asm volatile("global_store_dwordx4 %0, %1, off" :: "v"(hs32 + base + 512), "v"(l4) : "memory");
      }
    }

    if (t == TSTEPS - 1) {
      *(f32x4*)(hlast + (size_t)bb * HDIM + c0 + 4 * cp) = hn;
    } else {
      u32 tgt = (u32)(t + 2);
      for (;;) {
        u32 f = __hip_atomic_load(&flags[lane & 31], __ATOMIC_RELAXED, __HIP_MEMORY_SCOPE_AGENT);
        if (__all(f >= tgt)) break;
      }
    }
    nxz_c = nxz_n; nxh_c = nxh_n;
  }
}

// ---------------- host
extern "C" void kernel_launch(void* const* d_in, const int* in_sizes, int n_in,
                              void* d_out, int out_size, void* d_ws, size_t ws_size,
                              hipStream_t stream) {
  const float* x   = (const float*)d_in[0];
  const float* h0  = (const float*)d_in[1];
  const float* Wxz = (const float*)d_in[2];
  // d_in[3] = bxz: cancels inside BatchNorm -> unused
  const float* gz  = (const float*)d_in[4];
  const float* bz  = (const float*)d_in[5];
  const float* Whz = (const float*)d_in[6];
  const float* bhz = (const float*)d_in[7];
  const float* Wxh = (const float*)d_in[8];
  // d_in[9] = bxh: cancels in BN -> unused
  const float* gh  = (const float*)d_in[10];
  const float* bh  = (const float*)d_in[11];
  const float* Whh = (const float*)d_in[12];
  const float* bhh = (const float*)d_in[13];

  float* out_x = (float*)d_out;
  float* out_h = out_x + (size_t)MROWS * HDIM;

  char* w = (char*)d_ws;
  u16* xsp = (u16*)w;  w += (size_t)MROWS * KP * 2;            // 64 MB
  u16* wxp[4];
  for (int i = 0; i < 4; ++i) { wxp[i] = (u16*)w; w += (size_t)HDIM * KP * 2; }  // 4x4MB
  float* Pz = (float*)w;  w += (size_t)MROWS * HDIM * 4;       // 64 MB
  float* Ph = (float*)w;  w += (size_t)MROWS * HDIM * 4;       // 64 MB
  u32* hbufw = (u32*)w;   w += (size_t)2 * BATCH * 512 * 4;    // 128 KB
  u32* flags = (u32*)w;   w += 64 * 4;

  cast_split<<<(MROWS * HDIM + 255) / 256, 256, 0, stream>>>(x, xsp, MROWS * HDIM);
  for (int l = 0; l < 2; ++l) {
    cast_split<<<(HDIM * HDIM + 255) / 256, 256, 0, stream>>>(Wxz + (size_t)l * HDIM * HDIM, wxp[l * 2 + 0], HDIM * HDIM);
    cast_split<<<(HDIM * HDIM + 255) / 256, 256, 0, stream>>>(Wxh + (size_t)l * HDIM * HDIM, wxp[l * 2 + 1], HDIM * HDIM);
  }

  for (int l = 0; l < 2; ++l) {
    dim3 gg(HDIM / 128, MROWS / 128, 2);
    gemm_bt<<<gg, 256, 0, stream>>>(xsp, wxp[l * 2 + 0], wxp[l * 2 + 1], Pz, Ph);
    bn_inplace<<<dim3((TSTEPS * HDIM) / 256, 2), 256, 0, stream>>>(
        Pz, Ph,
        gz + (size_t)l * HDIM, bz + (size_t)l * HDIM, bhz + (size_t)l * HDIM,
        gh + (size_t)l * HDIM, bh + (size_t)l * HDIM, bhh + (size_t)l * HDIM);
    init_bar<<<1, 64, 0, stream>>>(flags);
    ligru_rec<<<NWG, 256, 0, stream>>>(
        Pz, Ph,
        Whz + (size_t)l * HDIM * HDIM, Whh + (size_t)l * HDIM * HDIM, h0,
        (l == 0) ? xsp : (u16*)nullptr,
        (l == 0) ? (float*)nullptr : out_x,
        out_h + (size_t)l * BATCH * HDIM,
        hbufw, flags);
  }
}